// Round 1
// baseline (1435.605 us; speedup 1.0000x reference)
//
#include <hip/hip_runtime.h>
#include <hip/hip_bf16.h>

#define H_  1024
#define B_  32
#define S_  2048
#define K2_ 2048   // 2*H

typedef __attribute__((ext_vector_type(8))) short short8;
typedef __attribute__((ext_vector_type(4))) float floatx4;

__device__ __forceinline__ unsigned short f2bf(float x) {
    unsigned int u = __float_as_uint(x);
    u += 0x7fffu + ((u >> 16) & 1u);   // round-to-nearest-even
    return (unsigned short)(u >> 16);
}

__device__ __forceinline__ float fast_tanh(float x) {
    // tanh(x) = 1 - 2/(e^{2x}+1); exact at +-inf, ~1e-7 rel error
    float e = __expf(2.0f * x);
    return 1.0f - 2.0f / (e + 1.0f);
}

// ---------------- wq[b][n] = W_b[n] + U_b[n] + sum_h dh[b][h] * W_w[n][h] ----------------
__global__ __launch_bounds__(256)
void wq_k(const float* __restrict__ dh, const float* __restrict__ Ww,
          const float* __restrict__ Wb, const float* __restrict__ Ub,
          float* __restrict__ wqbuf)
{
    const int b = blockIdx.x;
    const int tid = threadIdx.x;
    __shared__ float dhs[H_];
    for (int h = tid; h < H_; h += 256) dhs[h] = dh[b * H_ + h];
    __syncthreads();
    for (int n = tid; n < H_; n += 256) {
        const float4* row = (const float4*)(Ww + (size_t)n * H_);
        float acc = 0.f;
        #pragma unroll 4
        for (int h4 = 0; h4 < H_ / 4; h4++) {
            float4 wv = row[h4];
            acc += wv.x * dhs[h4 * 4 + 0] + wv.y * dhs[h4 * 4 + 1]
                 + wv.z * dhs[h4 * 4 + 2] + wv.w * dhs[h4 * 4 + 3];
        }
        wqbuf[b * H_ + n] = acc + Wb[n] + Ub[n];
    }
}

// ---------------- fused GEMM + tanh + V-dot -> partial scores ----------------
// C[m][n] = sum_k enc[b][m][k] * U_w[n][k]  (U_w is already [N][K] = B^T layout)
// partial[b][nt][m] = sum_{n in tile} V_w[n] * tanh(wq[b][n] + C[m][n])
__global__ __launch_bounds__(256)
void gemm_scores(const float* __restrict__ enc, const float* __restrict__ Uw,
                 const float* __restrict__ wqbuf, const float* __restrict__ Vw,
                 float* __restrict__ partial)
{
    const int b   = blockIdx.z;
    const int mt  = blockIdx.x;   // 16 tiles of 128 rows (s)
    const int nt  = blockIdx.y;   // 8 tiles of 128 cols (hidden)
    const int tid = threadIdx.x;
    const int wave = tid >> 6;
    const int lane = tid & 63;

    __shared__ unsigned short As[128][32];
    __shared__ unsigned short Bs[128][32];
    __shared__ float sc[2][128];

    const float* Ab = enc + ((size_t)b * S_ + (size_t)mt * 128) * K2_;
    const float* Bb = Uw + (size_t)nt * 128 * K2_;

    floatx4 acc[4][4];
    #pragma unroll
    for (int i = 0; i < 4; i++)
        #pragma unroll
        for (int j = 0; j < 4; j++)
            acc[i][j] = (floatx4){0.f, 0.f, 0.f, 0.f};

    const int wm  = (wave & 1) * 64;   // wave's m offset within 128
    const int wn  = (wave >> 1) * 64;  // wave's n offset within 128
    const int l15 = lane & 15;
    const int kq  = (lane >> 4) * 8;   // k offset of this lane's fragment

    for (int ks = 0; ks < K2_; ks += 32) {
        // stage 128x32 fp32 -> bf16 for both A and B; 4 float4 per thread per matrix
        #pragma unroll
        for (int i = 0; i < 4; i++) {
            int lin = tid + 256 * i;       // 0..1023
            int row = lin >> 3;            // 0..127
            int kk  = (lin & 7) << 2;      // 0..28
            float4 av = *(const float4*)(Ab + (size_t)row * K2_ + ks + kk);
            float4 bv = *(const float4*)(Bb + (size_t)row * K2_ + ks + kk);
            ushort4 a4 = { f2bf(av.x), f2bf(av.y), f2bf(av.z), f2bf(av.w) };
            ushort4 b4 = { f2bf(bv.x), f2bf(bv.y), f2bf(bv.z), f2bf(bv.w) };
            *(ushort4*)&As[row][kk] = a4;
            *(ushort4*)&Bs[row][kk] = b4;
        }
        __syncthreads();

        short8 af[4], bfr[4];
        #pragma unroll
        for (int t = 0; t < 4; t++) {
            af[t]  = *(const short8*)&As[wm + t * 16 + l15][kq];
            bfr[t] = *(const short8*)&Bs[wn + t * 16 + l15][kq];
        }
        #pragma unroll
        for (int tm = 0; tm < 4; tm++)
            #pragma unroll
            for (int tn = 0; tn < 4; tn++)
                acc[tm][tn] = __builtin_amdgcn_mfma_f32_16x16x32_bf16(
                    af[tm], bfr[tn], acc[tm][tn], 0, 0, 0);
        __syncthreads();
    }

    // epilogue: rs[tm][r] = sum over this wave's 64 n of V_w[n]*tanh(wq[n]+C)
    float rs[4][4];
    #pragma unroll
    for (int tm = 0; tm < 4; tm++)
        #pragma unroll
        for (int r = 0; r < 4; r++) rs[tm][r] = 0.f;

    #pragma unroll
    for (int tn = 0; tn < 4; tn++) {
        int ng = nt * 128 + wn + tn * 16 + l15;
        float vw = Vw[ng];
        float wv = wqbuf[b * H_ + ng];
        #pragma unroll
        for (int tm = 0; tm < 4; tm++)
            #pragma unroll
            for (int r = 0; r < 4; r++)
                rs[tm][r] += vw * fast_tanh(acc[tm][tn][r] + wv);
    }
    // reduce across the 16 lanes holding different n (cols)
    #pragma unroll
    for (int tm = 0; tm < 4; tm++)
        #pragma unroll
        for (int r = 0; r < 4; r++) {
            float v = rs[tm][r];
            v += __shfl_xor(v, 1, 64);
            v += __shfl_xor(v, 2, 64);
            v += __shfl_xor(v, 4, 64);
            v += __shfl_xor(v, 8, 64);
            rs[tm][r] = v;
        }
    if (l15 == 0) {
        int q = lane >> 4;
        #pragma unroll
        for (int tm = 0; tm < 4; tm++)
            #pragma unroll
            for (int r = 0; r < 4; r++)
                sc[wave >> 1][wm + tm * 16 + q * 4 + r] = rs[tm][r];
    }
    __syncthreads();
    if (tid < 128)
        partial[(size_t)(b * 8 + nt) * S_ + mt * 128 + tid] = sc[0][tid] + sc[1][tid];
}

// ---------------- softmax over S per batch ----------------
__global__ __launch_bounds__(256)
void softmax_k(const float* __restrict__ partial, float* __restrict__ weights)
{
    const int b = blockIdx.x;
    const int tid = threadIdx.x;
    __shared__ float scores[S_];
    __shared__ float redm[4], reds[4];

    for (int s = tid; s < S_; s += 256) {
        float v = 0.f;
        #pragma unroll
        for (int nt = 0; nt < 8; nt++) v += partial[(size_t)(b * 8 + nt) * S_ + s];
        scores[s] = v;
    }
    __syncthreads();

    float m = -1e30f;
    for (int s = tid; s < S_; s += 256) m = fmaxf(m, scores[s]);
    #pragma unroll
    for (int off = 32; off > 0; off >>= 1) m = fmaxf(m, __shfl_xor(m, off, 64));
    if ((tid & 63) == 0) redm[tid >> 6] = m;
    __syncthreads();
    m = fmaxf(fmaxf(redm[0], redm[1]), fmaxf(redm[2], redm[3]));

    float sum = 0.f;
    for (int s = tid; s < S_; s += 256) {
        float e = __expf(scores[s] - m);
        scores[s] = e;
        sum += e;
    }
    #pragma unroll
    for (int off = 32; off > 0; off >>= 1) sum += __shfl_xor(sum, off, 64);
    if ((tid & 63) == 0) reds[tid >> 6] = sum;
    __syncthreads();
    sum = reds[0] + reds[1] + reds[2] + reds[3];
    float inv = 1.0f / sum;
    for (int s = tid; s < S_; s += 256) weights[b * S_ + s] = scores[s] * inv;
}

// ---------------- context[b][d] = sum_s w[b][s] * enc[b][s][d] ----------------
__global__ __launch_bounds__(256)
void context_k(const float* __restrict__ enc, const float* __restrict__ weights,
               float* __restrict__ out)
{
    const int b = blockIdx.y;
    const int d = blockIdx.x * 256 + threadIdx.x;   // blockIdx.x in [0,8)
    const int tid = threadIdx.x;
    __shared__ float w[S_];
    for (int s = tid; s < S_; s += 256) w[s] = weights[b * S_ + s];
    __syncthreads();

    const float* e = enc + (size_t)b * S_ * K2_ + d;
    float a0 = 0.f, a1 = 0.f, a2 = 0.f, a3 = 0.f;
    for (int s = 0; s < S_; s += 4) {
        a0 += w[s + 0] * e[(size_t)(s + 0) * K2_];
        a1 += w[s + 1] * e[(size_t)(s + 1) * K2_];
        a2 += w[s + 2] * e[(size_t)(s + 2) * K2_];
        a3 += w[s + 3] * e[(size_t)(s + 3) * K2_];
    }
    out[b * K2_ + d] = (a0 + a1) + (a2 + a3);
}

extern "C" void kernel_launch(void* const* d_in, const int* in_sizes, int n_in,
                              void* d_out, int out_size, void* d_ws, size_t ws_size,
                              hipStream_t stream)
{
    const float* enc = (const float*)d_in[0];  // [32, 2048, 2048]
    const float* dh  = (const float*)d_in[1];  // [1, 32, 1024]
    const float* Ww  = (const float*)d_in[2];  // [1024, 1024]
    const float* Wb  = (const float*)d_in[3];  // [1024]
    const float* Uw  = (const float*)d_in[4];  // [1024, 2048]
    const float* Ub  = (const float*)d_in[5];  // [1024]
    const float* Vw  = (const float*)d_in[6];  // [1, 1024]
    // d_in[7] = V_b: unused — softmax is shift-invariant.
    float* out = (float*)d_out;                // [32, 1, 2048] fp32

    float* wqbuf   = (float*)d_ws;             // 32*1024 floats
    float* partial = wqbuf + B_ * H_;          // 32*8*2048 floats
    float* weights = partial + B_ * 8 * S_;    // 32*2048 floats
    // total ws use: ~2.4 MB

    wq_k<<<dim3(B_), dim3(256), 0, stream>>>(dh, Ww, Wb, Ub, wqbuf);
    gemm_scores<<<dim3(16, 8, B_), dim3(256), 0, stream>>>(enc, Uw, wqbuf, Vw, partial);
    softmax_k<<<dim3(B_), dim3(256), 0, stream>>>(partial, weights);
    context_k<<<dim3(8, B_), dim3(256), 0, stream>>>(enc, weights, out);
}

// Round 2
// 1212.145 us; speedup vs baseline: 1.1844x; 1.1844x over previous
//
#include <hip/hip_runtime.h>
#include <hip/hip_bf16.h>

#define H_  1024
#define B_  32
#define S_  2048
#define K2_ 2048   // 2*H

typedef __attribute__((ext_vector_type(8))) short short8;
typedef __attribute__((ext_vector_type(4))) float floatx4;
typedef __attribute__((ext_vector_type(8))) unsigned short ushortx8;

__device__ __forceinline__ unsigned short f2bf(float x) {
    unsigned int u = __float_as_uint(x);
    u += 0x7fffu + ((u >> 16) & 1u);   // round-to-nearest-even
    return (unsigned short)(u >> 16);
}

__device__ __forceinline__ float fast_tanh(float x) {
    float e = __expf(2.0f * x);
    return 1.0f - 2.0f / (e + 1.0f);
}

__device__ __forceinline__ void gload_lds16(const void* g, void* l) {
    __builtin_amdgcn_global_load_lds(
        (const __attribute__((address_space(1))) unsigned int*)g,
        (__attribute__((address_space(3))) unsigned int*)l, 16, 0, 0);
}

// ---------------- fp32 -> bf16 bulk convert ----------------
__global__ __launch_bounds__(256)
void cvt_bf16_k(const float* __restrict__ in, unsigned short* __restrict__ out, long long n8)
{
    long long i = (long long)blockIdx.x * 256 + threadIdx.x;
    long long stride = (long long)gridDim.x * 256;
    for (; i < n8; i += stride) {
        const float4* p = (const float4*)in + i * 2;
        float4 a = p[0], b = p[1];
        ushortx8 o = { f2bf(a.x), f2bf(a.y), f2bf(a.z), f2bf(a.w),
                       f2bf(b.x), f2bf(b.y), f2bf(b.z), f2bf(b.w) };
        *(ushortx8*)(out + i * 8) = o;
    }
}

// ---------------- wq[b][n] = W_b[n] + U_b[n] + sum_h dh[b][h] * W_w[n][h] ----------------
__global__ __launch_bounds__(256)
void wq_k(const float* __restrict__ dh, const float* __restrict__ Ww,
          const float* __restrict__ Wb, const float* __restrict__ Ub,
          float* __restrict__ wqbuf)
{
    const int b = blockIdx.y;
    const int n = blockIdx.x * 256 + threadIdx.x;
    const int tid = threadIdx.x;
    __shared__ float dhs[H_];
    for (int h = tid; h < H_; h += 256) dhs[h] = dh[b * H_ + h];
    __syncthreads();
    const float4* row = (const float4*)(Ww + (size_t)n * H_);
    float acc = 0.f;
    #pragma unroll 4
    for (int h4 = 0; h4 < H_ / 4; h4++) {
        float4 wv = row[h4];
        acc += wv.x * dhs[h4 * 4 + 0] + wv.y * dhs[h4 * 4 + 1]
             + wv.z * dhs[h4 * 4 + 2] + wv.w * dhs[h4 * 4 + 3];
    }
    wqbuf[b * H_ + n] = acc + Wb[n] + Ub[n];
}

// ---------------- fast path: bf16 GEMM with global_load_lds staging ----------------
// C[m][n] = sum_k encb[b][m][k] * Uwb[n][k]; epilogue: V-dot of tanh(C + wq)
__global__ __launch_bounds__(256)
void gemm_scores_bf16(const unsigned short* __restrict__ encb,
                      const unsigned short* __restrict__ Uwb,
                      const float* __restrict__ wqbuf, const float* __restrict__ Vw,
                      float* __restrict__ partial)
{
    const int b   = blockIdx.z;
    const int mt  = blockIdx.x;   // 16 tiles of 128 rows (s)
    const int nt  = blockIdx.y;   // 8 tiles of 128 cols (hidden)
    const int tid = threadIdx.x;
    const int wave = tid >> 6;
    const int lane = tid & 63;

    __shared__ unsigned short As[128 * 32];
    __shared__ unsigned short Bs[128 * 32];
    __shared__ float sc[2][128];

    const unsigned short* Ag = encb + ((size_t)b * S_ + (size_t)mt * 128) * K2_;
    const unsigned short* Bg = Uwb + (size_t)nt * 128 * K2_;

    floatx4 acc[4][4];
    #pragma unroll
    for (int i = 0; i < 4; i++)
        #pragma unroll
        for (int j = 0; j < 4; j++)
            acc[i][j] = (floatx4){0.f, 0.f, 0.f, 0.f};

    const int wm  = (wave & 1) * 64;
    const int wn  = (wave >> 1) * 64;
    const int l15 = lane & 15;
    const int kq  = (lane >> 4) * 8;

    // staging addressing: wave w covers rows [w*32, w*32+31]; per instruction j
    // (j=0,1) rows w*32 + j*16 + lane/4, k-chunk (lane&3)*8. LDS dest is
    // wave-uniform base + lane*16B (global_load_lds scatter rule).
    const int r0 = lane >> 2;
    const int ke = (lane & 3) * 8;
    const unsigned short* aptr = Ag + (size_t)(wave * 32 + r0) * K2_ + ke;
    const unsigned short* bptr = Bg + (size_t)(wave * 32 + r0) * K2_ + ke;
    unsigned short* AldsA = As + wave * 1024;
    unsigned short* AldsB = Bs + wave * 1024;

    for (int ks = 0; ks < K2_; ks += 32) {
        gload_lds16(aptr + ks,             AldsA);
        gload_lds16(aptr + 16 * K2_ + ks,  AldsA + 512);
        gload_lds16(bptr + ks,             AldsB);
        gload_lds16(bptr + 16 * K2_ + ks,  AldsB + 512);
        __syncthreads();

        short8 af[4], bfr[4];
        #pragma unroll
        for (int t = 0; t < 4; t++) {
            af[t]  = *(const short8*)&As[(wm + t * 16 + l15) * 32 + kq];
            bfr[t] = *(const short8*)&Bs[(wn + t * 16 + l15) * 32 + kq];
        }
        #pragma unroll
        for (int tm = 0; tm < 4; tm++)
            #pragma unroll
            for (int tn = 0; tn < 4; tn++)
                acc[tm][tn] = __builtin_amdgcn_mfma_f32_16x16x32_bf16(
                    af[tm], bfr[tn], acc[tm][tn], 0, 0, 0);
        __syncthreads();
    }

    float rs[4][4];
    #pragma unroll
    for (int tm = 0; tm < 4; tm++)
        #pragma unroll
        for (int r = 0; r < 4; r++) rs[tm][r] = 0.f;

    #pragma unroll
    for (int tn = 0; tn < 4; tn++) {
        int ng = nt * 128 + wn + tn * 16 + l15;
        float vw = Vw[ng];
        float wv = wqbuf[b * H_ + ng];
        #pragma unroll
        for (int tm = 0; tm < 4; tm++)
            #pragma unroll
            for (int r = 0; r < 4; r++)
                rs[tm][r] += vw * fast_tanh(acc[tm][tn][r] + wv);
    }
    #pragma unroll
    for (int tm = 0; tm < 4; tm++)
        #pragma unroll
        for (int r = 0; r < 4; r++) {
            float v = rs[tm][r];
            v += __shfl_xor(v, 1, 64);
            v += __shfl_xor(v, 2, 64);
            v += __shfl_xor(v, 4, 64);
            v += __shfl_xor(v, 8, 64);
            rs[tm][r] = v;
        }
    if (l15 == 0) {
        int q = lane >> 4;
        #pragma unroll
        for (int tm = 0; tm < 4; tm++)
            #pragma unroll
            for (int r = 0; r < 4; r++)
                sc[wave >> 1][wm + tm * 16 + q * 4 + r] = rs[tm][r];
    }
    __syncthreads();
    if (tid < 128)
        partial[(size_t)(b * 8 + nt) * S_ + mt * 128 + tid] = sc[0][tid] + sc[1][tid];
}

// ---------------- fallback: round-1 inline-convert GEMM (if ws too small) ----------------
__global__ __launch_bounds__(256)
void gemm_scores_f32(const float* __restrict__ enc, const float* __restrict__ Uw,
                     const float* __restrict__ wqbuf, const float* __restrict__ Vw,
                     float* __restrict__ partial)
{
    const int b   = blockIdx.z;
    const int mt  = blockIdx.x;
    const int nt  = blockIdx.y;
    const int tid = threadIdx.x;
    const int wave = tid >> 6;
    const int lane = tid & 63;

    __shared__ unsigned short As[128][32];
    __shared__ unsigned short Bs[128][32];
    __shared__ float sc[2][128];

    const float* Ab = enc + ((size_t)b * S_ + (size_t)mt * 128) * K2_;
    const float* Bb = Uw + (size_t)nt * 128 * K2_;

    floatx4 acc[4][4];
    #pragma unroll
    for (int i = 0; i < 4; i++)
        #pragma unroll
        for (int j = 0; j < 4; j++)
            acc[i][j] = (floatx4){0.f, 0.f, 0.f, 0.f};

    const int wm  = (wave & 1) * 64;
    const int wn  = (wave >> 1) * 64;
    const int l15 = lane & 15;
    const int kq  = (lane >> 4) * 8;

    for (int ks = 0; ks < K2_; ks += 32) {
        #pragma unroll
        for (int i = 0; i < 4; i++) {
            int lin = tid + 256 * i;
            int row = lin >> 3;
            int kk  = (lin & 7) << 2;
            float4 av = *(const float4*)(Ab + (size_t)row * K2_ + ks + kk);
            float4 bv = *(const float4*)(Bb + (size_t)row * K2_ + ks + kk);
            ushort4 a4 = { f2bf(av.x), f2bf(av.y), f2bf(av.z), f2bf(av.w) };
            ushort4 b4 = { f2bf(bv.x), f2bf(bv.y), f2bf(bv.z), f2bf(bv.w) };
            *(ushort4*)&As[row][kk] = a4;
            *(ushort4*)&Bs[row][kk] = b4;
        }
        __syncthreads();

        short8 af[4], bfr[4];
        #pragma unroll
        for (int t = 0; t < 4; t++) {
            af[t]  = *(const short8*)&As[wm + t * 16 + l15][kq];
            bfr[t] = *(const short8*)&Bs[wn + t * 16 + l15][kq];
        }
        #pragma unroll
        for (int tm = 0; tm < 4; tm++)
            #pragma unroll
            for (int tn = 0; tn < 4; tn++)
                acc[tm][tn] = __builtin_amdgcn_mfma_f32_16x16x32_bf16(
                    af[tm], bfr[tn], acc[tm][tn], 0, 0, 0);
        __syncthreads();
    }

    float rs[4][4];
    #pragma unroll
    for (int tm = 0; tm < 4; tm++)
        #pragma unroll
        for (int r = 0; r < 4; r++) rs[tm][r] = 0.f;

    #pragma unroll
    for (int tn = 0; tn < 4; tn++) {
        int ng = nt * 128 + wn + tn * 16 + l15;
        float vw = Vw[ng];
        float wv = wqbuf[b * H_ + ng];
        #pragma unroll
        for (int tm = 0; tm < 4; tm++)
            #pragma unroll
            for (int r = 0; r < 4; r++)
                rs[tm][r] += vw * fast_tanh(acc[tm][tn][r] + wv);
    }
    #pragma unroll
    for (int tm = 0; tm < 4; tm++)
        #pragma unroll
        for (int r = 0; r < 4; r++) {
            float v = rs[tm][r];
            v += __shfl_xor(v, 1, 64);
            v += __shfl_xor(v, 2, 64);
            v += __shfl_xor(v, 4, 64);
            v += __shfl_xor(v, 8, 64);
            rs[tm][r] = v;
        }
    if (l15 == 0) {
        int q = lane >> 4;
        #pragma unroll
        for (int tm = 0; tm < 4; tm++)
            #pragma unroll
            for (int r = 0; r < 4; r++)
                sc[wave >> 1][wm + tm * 16 + q * 4 + r] = rs[tm][r];
    }
    __syncthreads();
    if (tid < 128)
        partial[(size_t)(b * 8 + nt) * S_ + mt * 128 + tid] = sc[0][tid] + sc[1][tid];
}

// ---------------- softmax over S per batch ----------------
__global__ __launch_bounds__(256)
void softmax_k(const float* __restrict__ partial, float* __restrict__ weights)
{
    const int b = blockIdx.x;
    const int tid = threadIdx.x;
    __shared__ float scores[S_];
    __shared__ float redm[4], reds[4];

    for (int s = tid; s < S_; s += 256) {
        float v = 0.f;
        #pragma unroll
        for (int nt = 0; nt < 8; nt++) v += partial[(size_t)(b * 8 + nt) * S_ + s];
        scores[s] = v;
    }
    __syncthreads();

    float m = -1e30f;
    for (int s = tid; s < S_; s += 256) m = fmaxf(m, scores[s]);
    #pragma unroll
    for (int off = 32; off > 0; off >>= 1) m = fmaxf(m, __shfl_xor(m, off, 64));
    if ((tid & 63) == 0) redm[tid >> 6] = m;
    __syncthreads();
    m = fmaxf(fmaxf(redm[0], redm[1]), fmaxf(redm[2], redm[3]));

    float sum = 0.f;
    for (int s = tid; s < S_; s += 256) {
        float e = __expf(scores[s] - m);
        scores[s] = e;
        sum += e;
    }
    #pragma unroll
    for (int off = 32; off > 0; off >>= 1) sum += __shfl_xor(sum, off, 64);
    if ((tid & 63) == 0) reds[tid >> 6] = sum;
    __syncthreads();
    sum = reds[0] + reds[1] + reds[2] + reds[3];
    float inv = 1.0f / sum;
    for (int s = tid; s < S_; s += 256) weights[b * S_ + s] = scores[s] * inv;
}

// ---------------- context: partial over 8 s-chunks, float4 columns ----------------
__global__ __launch_bounds__(256)
void context2_k(const float* __restrict__ enc, const float* __restrict__ weights,
                float* __restrict__ pctx)
{
    const int b = blockIdx.z, scnk = blockIdx.y, dblk = blockIdx.x;
    const int tid = threadIdx.x;
    __shared__ float w[256];
    w[tid] = weights[b * S_ + scnk * 256 + tid];
    __syncthreads();

    const float4* e = (const float4*)(enc + ((size_t)b * S_ + scnk * 256) * K2_)
                      + dblk * 256 + tid;
    float4 a0 = {0,0,0,0}, a1 = {0,0,0,0};
    #pragma unroll 4
    for (int s = 0; s < 256; s += 2) {
        float4 v0 = e[(size_t)s * 512];
        float4 v1 = e[(size_t)(s + 1) * 512];
        float w0 = w[s], w1 = w[s + 1];
        a0.x += w0 * v0.x; a0.y += w0 * v0.y; a0.z += w0 * v0.z; a0.w += w0 * v0.w;
        a1.x += w1 * v1.x; a1.y += w1 * v1.y; a1.z += w1 * v1.z; a1.w += w1 * v1.w;
    }
    float4 acc = { a0.x + a1.x, a0.y + a1.y, a0.z + a1.z, a0.w + a1.w };
    float4* o = (float4*)(pctx + (size_t)(b * 8 + scnk) * K2_) + dblk * 256 + tid;
    *o = acc;
}

__global__ __launch_bounds__(256)
void ctx_reduce_k(const float* __restrict__ pctx, float* __restrict__ out)
{
    const int i = blockIdx.x * 256 + threadIdx.x;   // 0..65535
    const int b = i >> 11, d = i & 2047;
    float s = 0.f;
    #pragma unroll
    for (int c = 0; c < 8; c++) s += pctx[(size_t)(b * 8 + c) * K2_ + d];
    out[i] = s;
}

extern "C" void kernel_launch(void* const* d_in, const int* in_sizes, int n_in,
                              void* d_out, int out_size, void* d_ws, size_t ws_size,
                              hipStream_t stream)
{
    const float* enc = (const float*)d_in[0];  // [32, 2048, 2048]
    const float* dh  = (const float*)d_in[1];  // [1, 32, 1024]
    const float* Ww  = (const float*)d_in[2];  // [1024, 1024]
    const float* Wb  = (const float*)d_in[3];  // [1024]
    const float* Uw  = (const float*)d_in[4];  // [1024, 2048]
    const float* Ub  = (const float*)d_in[5];  // [1024]
    const float* Vw  = (const float*)d_in[6];  // [1, 1024]
    // d_in[7] = V_b: unused (softmax shift-invariant)
    float* out = (float*)d_out;                // [32, 1, 2048] fp32

    float* wqbuf   = (float*)d_ws;                         // 32*1024
    float* partial = wqbuf + B_ * H_;                      // 32*8*2048
    float* weights = partial + B_ * 8 * S_;                // 32*2048
    float* pctx    = weights + B_ * S_;                    // 32*8*2048
    size_t small_bytes = (size_t)(B_*H_ + B_*8*S_ + B_*S_ + B_*8*S_) * 4;  // ~4.4 MB
    unsigned short* Uwb  = (unsigned short*)((char*)d_ws + small_bytes);    // 4 MB
    unsigned short* encb = Uwb + (size_t)H_ * K2_;                          // 256 MB
    size_t need = small_bytes + (size_t)H_ * K2_ * 2 + (size_t)B_ * S_ * K2_ * 2;

    wq_k<<<dim3(4, B_), dim3(256), 0, stream>>>(dh, Ww, Wb, Ub, wqbuf);

    if (ws_size >= need) {
        long long n8_enc = (long long)B_ * S_ * K2_ / 8;
        long long n8_uw  = (long long)H_ * K2_ / 8;
        cvt_bf16_k<<<dim3(8192), dim3(256), 0, stream>>>(enc, encb, n8_enc);
        cvt_bf16_k<<<dim3(1024), dim3(256), 0, stream>>>(Uw, Uwb, n8_uw);
        gemm_scores_bf16<<<dim3(16, 8, B_), dim3(256), 0, stream>>>(encb, Uwb, wqbuf, Vw, partial);
    } else {
        gemm_scores_f32<<<dim3(16, 8, B_), dim3(256), 0, stream>>>(enc, Uw, wqbuf, Vw, partial);
    }

    softmax_k<<<dim3(B_), dim3(256), 0, stream>>>(partial, weights);
    context2_k<<<dim3(2, 8, B_), dim3(256), 0, stream>>>(enc, weights, pctx);
    ctx_reduce_k<<<dim3(256), dim3(256), 0, stream>>>(pctx, out);
}